// Round 12
// baseline (308.933 us; speedup 1.0000x reference)
//
#include <hip/hip_runtime.h>

typedef unsigned short ushort_t;
typedef short short8 __attribute__((ext_vector_type(8)));
typedef float f32x4 __attribute__((ext_vector_type(4)));
typedef ushort_t ushort8v __attribute__((ext_vector_type(8)));
typedef ushort_t ushort4v __attribute__((ext_vector_type(4)));

#define HWsz 16384
#define NHWsz 65536
// LDS strides (ushorts) for kA/kB/kCD padded tiles
#define YS 136

__device__ __forceinline__ float b2f(ushort_t u){ return __uint_as_float(((unsigned)u)<<16); }
__device__ __forceinline__ ushort_t f2b(float f){
  unsigned x = __float_as_uint(f);
  x += 0x7fffu + ((x>>16)&1u);
  return (ushort_t)(x>>16);
}
// tanh-form GELU: max |err| vs exact ~3e-4, below bf16 ulp at |x|~1+.
__device__ __forceinline__ float gelu_fast(float x){
  float t = x*x;
  float e = __expf(x*(1.5957691216f + 0.0713548163f*t));
  return x - x*__builtin_amdgcn_rcpf(1.0f + e);
}

// XOR-swizzled LDS byte offsets (row-bit into bank bits).
#define XSW(p, b) ((p)*256 + ((b) ^ (((p)&7)<<4)))   // 256B rows

// ---------------- kW: weight preprocessing (once per launch) ----------------
__global__ __launch_bounds__(256) void kW_cvt(const float* __restrict__ w1, const float* __restrict__ w2,
    const float* __restrict__ offw, const float* __restrict__ maskw, const float* __restrict__ dww,
    const float* __restrict__ pw, const float* __restrict__ offb, const float* __restrict__ mb,
    ushort_t* __restrict__ w1b, ushort_t* __restrict__ w2b, ushort_t* __restrict__ owmb,
    float* __restrict__ dwwT, ushort_t* __restrict__ pwh, ushort_t* __restrict__ pwl,
    float* __restrict__ obm){
  int i = blockIdx.x*256 + threadIdx.x;   // 65536
  w1b[i] = f2b(w1[i]);
  w2b[i] = f2b(w2[i]);
  if (i < 16384){
    int row = i >> 7, k = i & 127;
    float v = 0.f;
    if (row < 72) v = offw[row*128 + k];
    else if (row < 108) v = maskw[(row-72)*128 + k];
    owmb[i] = f2b(v);
    float pv = pw[i];
    ushort_t hi = f2b(pv);
    pwh[i] = hi;
    pwl[i] = f2b(pv - b2f(hi));
  }
  if (i < 1152){
    int k = i >> 7, c = i & 127;
    dwwT[i] = dww[c*9 + k];
  }
  if (i < 128){
    obm[i] = (i < 72) ? offb[i] : ((i < 108) ? mb[i-72] : 0.f);
  }
}

// ---------------- kA: LN1, NCHW fp32 -> NHWC bf16 ----------------
__global__ __launch_bounds__(256) void kA_ln1(const float* __restrict__ x,
    const float* __restrict__ w, const float* __restrict__ b,
    ushort_t* __restrict__ xcl){
  __shared__ float tile[128*66];
  __shared__ float psum[256], psq[256];
  __shared__ float ms[64], rs[64];
  int t = threadIdx.x;
  int pos0 = blockIdx.x * 64;
  int n = pos0 >> 14, hw0 = pos0 & 16383;
  const float* xb = x + (size_t)n*128*HWsz + hw0;
  for (int i=0;i<32;i++){
    int e = i*256+t;
    int c = e>>6, p = e&63;
    tile[c*66+p] = xb[(size_t)c*HWsz + p];
  }
  __syncthreads();
  {
    int part = t>>6, p = t&63;
    float s=0.f, q=0.f;
    for (int c=part*32; c<part*32+32; c++){ float v = tile[c*66+p]; s+=v; q+=v*v; }
    psum[part*64+p]=s; psq[part*64+p]=q;
  }
  __syncthreads();
  if (t<64){
    float s=psum[t]+psum[64+t]+psum[128+t]+psum[192+t];
    float q=psq[t]+psq[64+t]+psq[128+t]+psq[192+t];
    float m = s*(1.0f/128.0f);
    float v = q*(1.0f/128.0f)-m*m;
    ms[t]=m; rs[t]=rsqrtf(v+1e-6f);
  }
  __syncthreads();
  for (int i=0;i<32;i++){
    int e = i*256+t;
    int p = e>>7, c = e&127;
    float v = (tile[c*66+p]-ms[p])*rs[p]*w[c]+b[c];
    xcl[(size_t)(pos0+p)*128 + c] = f2b(v);
  }
}

// ---------------- kB: depthwise 3x3 + bias + LN + GELU ----------------
__global__ __launch_bounds__(256) void kB_dw(const ushort_t* __restrict__ xcl,
    const float* __restrict__ dwwT, const float* __restrict__ dwb,
    const float* __restrict__ lnw, const float* __restrict__ lnb,
    ushort_t* __restrict__ x1){
  __shared__ float partS[16*17], partQ[16*17];
  __shared__ float ms[16], rs[16];
  int t = threadIdx.x;
  int pos0 = blockIdx.x*16;
  int n = pos0>>14, hw0 = pos0&16383, h = hw0>>7, w0 = hw0&127;
  int pp = t>>4, l = t&15, ch0 = l*8;
  int w = w0 + pp;
  float acc[8];
  {
    float4 b0 = *(const float4*)(dwb + ch0);
    float4 b1 = *(const float4*)(dwb + ch0 + 4);
    acc[0]=b0.x; acc[1]=b0.y; acc[2]=b0.z; acc[3]=b0.w;
    acc[4]=b1.x; acc[5]=b1.y; acc[6]=b1.z; acc[7]=b1.w;
  }
  #pragma unroll
  for (int kh=0; kh<3; kh++){
    int hy = h + kh - 1;
    if ((unsigned)hy < 128u){
      #pragma unroll
      for (int kw=0; kw<3; kw++){
        int wx = w + kw - 1;
        if ((unsigned)wx < 128u){
          ushort8v xv = *(const ushort8v*)(xcl + ((size_t)(n*16384 + hy*128 + wx))*128 + ch0);
          const float* wr = dwwT + (kh*3+kw)*128 + ch0;
          float4 w0v = *(const float4*)(wr);
          float4 w1v = *(const float4*)(wr+4);
          acc[0] += b2f(xv[0])*w0v.x; acc[1] += b2f(xv[1])*w0v.y;
          acc[2] += b2f(xv[2])*w0v.z; acc[3] += b2f(xv[3])*w0v.w;
          acc[4] += b2f(xv[4])*w1v.x; acc[5] += b2f(xv[5])*w1v.y;
          acc[6] += b2f(xv[6])*w1v.z; acc[7] += b2f(xv[7])*w1v.w;
        }
      }
    }
  }
  {
    float s=0.f, q=0.f;
    #pragma unroll
    for (int j=0;j<8;j++){ s+=acc[j]; q+=acc[j]*acc[j]; }
    partS[pp*17+l]=s; partQ[pp*17+l]=q;
  }
  __syncthreads();
  {
    int p = t>>4, j = t&15;
    float s = partS[p*17+j];
    float q = partQ[p*17+j];
    s += __shfl_xor(s, 1);  q += __shfl_xor(q, 1);
    s += __shfl_xor(s, 2);  q += __shfl_xor(q, 2);
    s += __shfl_xor(s, 4);  q += __shfl_xor(q, 4);
    s += __shfl_xor(s, 8);  q += __shfl_xor(q, 8);
    if (j == 0){
      float m = s*(1.0f/128.0f);
      float var = q*(1.0f/128.0f) - m*m;
      ms[p]=m; rs[p]=rsqrtf(var+1e-6f);
    }
  }
  __syncthreads();
  {
    float m = ms[pp], r = rs[pp];
    float4 lw0 = *(const float4*)(lnw + ch0);
    float4 lw1 = *(const float4*)(lnw + ch0 + 4);
    float4 lb0 = *(const float4*)(lnb + ch0);
    float4 lb1 = *(const float4*)(lnb + ch0 + 4);
    float lw[8] = {lw0.x,lw0.y,lw0.z,lw0.w,lw1.x,lw1.y,lw1.z,lw1.w};
    float lb[8] = {lb0.x,lb0.y,lb0.z,lb0.w,lb1.x,lb1.y,lb1.z,lb1.w};
    ushort8v o;
    #pragma unroll
    for (int j=0;j<8;j++){
      float v = (acc[j]-m)*r*lw[j]+lb[j];
      o[j] = f2b(gelu_fast(v));
    }
    *(ushort8v*)(x1 + (size_t)(pos0+pp)*128 + ch0) = o;
  }
}

// ---------------- kCD v3: + LDS sampling window (5 rows x 22 cols x 128 ch) ----------------
// r11 lesson: kCD is VMEM-issue bound (occupancy change neutral). The gather's 36 corner
// loads/thread mostly land within +-2 px of the reference point (offsets ~ N(0,0.8)), so
// stage a 5x22x128 window of x1 in LDS (28.2 KB, exact copies) and serve in-window
// corners from LDS; out-of-window corners use the identical global load via an
// exec-masked branch (global VMEM issues only when some active lane needs it).
// Expected VMEM/thread: 7 staging + ~0.2*36 fallback ~= 14 vs 36.
#define RS 120
__global__ __launch_bounds__(256) void kCD_dcn(const ushort_t* __restrict__ x1,
    const ushort_t* __restrict__ owmb, const float* __restrict__ obm,
    ushort_t* __restrict__ dcnout){
  __shared__ __align__(16) ushort_t xLb[16*YS];
  __shared__ float raw[16*RS];
  __shared__ __align__(16) ushort_t swin[5*2816];   // 5 rows x 22 cols x 128 ch bf16
  int t = threadIdx.x;
  int pos0 = blockIdx.x*16;
  int n = pos0>>14, hw0 = pos0&16383, h = hw0>>7, w0 = hw0&127;
  const size_t imgbase = (size_t)n*16384*128;

  *(ushort8v*)(xLb + (t>>4)*YS + (t&15)*8) = *(const ushort8v*)(x1 + (size_t)pos0*128 + t*8);

  // stage sampling window: rows r0..r0+4, cols c0..c0+21 (always fully in-image)
  int r0 = min(max(h-2,0),123);
  int c0 = min(max(w0-3,0),106);
  {
    const ushort_t* wb = x1 + imgbase + ((size_t)(r0*128 + c0))*128;
    #pragma unroll
    for (int i=0;i<7;i++){
      int e = i*256 + t;                 // 1760 x 16B units (5 rows x 352 units)
      if (e < 1760){
        int row = e/352, rem = e - row*352;
        *(ushort8v*)(swin + row*2816 + rem*8) = *(const ushort8v*)(wb + (size_t)row*16384 + rem*8);
      }
    }
  }
  __syncthreads();

  // MFMA linear, operand-swapped: D-row = weight-row, D-col = position
  {
    int wave = t>>6, lane = t&63;
    int ma = lane&15, quad = lane>>4;
    short8 afrag[4];
    #pragma unroll
    for (int ks=0; ks<4; ks++)
      afrag[ks] = *(const short8*)(xLb + ma*YS + ks*32 + quad*8);
    f32x4 acc[2];
    acc[0] = (f32x4){0.f,0.f,0.f,0.f};
    acc[1] = (f32x4){0.f,0.f,0.f,0.f};
    #pragma unroll
    for (int tile=0; tile<2; tile++){
      const ushort_t* brow = owmb + (size_t)(wave*32 + tile*16 + ma)*128 + quad*8;
      #pragma unroll
      for (int ks=0; ks<4; ks++){
        short8 bfrag = *(const short8*)(brow + ks*32);
        acc[tile] = __builtin_amdgcn_mfma_f32_16x16x32_bf16(bfrag, afrag[ks], acc[tile], 0,0,0);
      }
    }
    #pragma unroll
    for (int tile=0; tile<2; tile++){
      int row0 = wave*32 + tile*16 + quad*4;
      if (row0 < 112){
        f32x4 bias4 = *(const f32x4*)(obm + row0);
        f32x4 o;
        #pragma unroll
        for (int r=0;r<4;r++) o[r] = acc[tile][r] + bias4[r];
        *(f32x4*)(raw + ma*RS + row0) = o;
      }
    }
  }
  __syncthreads();

  if (t < 64){
    int p = t>>2, g = t&3;
    float* mr = raw + p*RS + 72 + g*9;
    float mx = -1e30f;
    for (int q=0;q<9;q++) mx = fmaxf(mx, mr[q]);
    float e[9]; float ssum=0.f;
    for (int q=0;q<9;q++){ e[q]=expf(mr[q]-mx); ssum+=e[q]; }
    float inv = 1.0f/ssum;
    for (int q=0;q<9;q++) mr[q] = e[q]*inv;
  }
  __syncthreads();

  // sampling: per-thread descriptors; LDS window fast path, global fallback
  {
    int pp = t>>4, l = t&15;
    int ch0 = l*8, g = l>>2;
    const ushort_t* ib = x1 + imgbase + ch0;
    const ushort_t* sw = swin + ch0;
    const float* rbase = raw + pp*RS;
    float acc[8];
    #pragma unroll
    for (int j=0;j<8;j++) acc[j]=0.f;
    float bx = (float)(w0 + pp - 1);
    float by = (float)(h - 1);
    #pragma unroll
    for (int p=0;p<9;p++){
      const int i = p/3, j = p - i*3;
      float ox = rbase[2*(g*9+p)];
      float oy = rbase[2*(g*9+p)+1];
      float mval = rbase[72 + g*9 + p];
      float px = bx + (float)i + ox;
      float py = by + (float)j + oy;
      float fx0 = floorf(px), fy0 = floorf(py);
      int ix0 = (int)fx0, iy0 = (int)fy0;
      float fx = px - fx0, fy = py - fy0;
      float vx0 = ((unsigned)ix0     < 128u) ? 1.f : 0.f;
      float vx1 = ((unsigned)(ix0+1) < 128u) ? 1.f : 0.f;
      float vy0 = ((unsigned)iy0     < 128u) ? 1.f : 0.f;
      float vy1 = ((unsigned)(iy0+1) < 128u) ? 1.f : 0.f;
      int cx0 = min(max(ix0,0),127), cx1 = min(max(ix0+1,0),127);
      int cy0 = min(max(iy0,0),127), cy1 = min(max(iy0+1,0),127);
      float wx00 = (1.f-fx)*(1.f-fy)*mval*vx0*vy0;
      float wx10 = fx*(1.f-fy)*mval*vx1*vy0;
      float wx01 = (1.f-fx)*fy*mval*vx0*vy1;
      float wx11 = fx*fy*mval*vx1*vy1;
      int ry0 = cy0 - r0, ry1 = cy1 - r0;
      int rx0 = cx0 - c0, rx1 = cx1 - c0;
      ushort8v v00, v10, v01, v11;
      if (((unsigned)ry0 < 5u) & ((unsigned)rx0 < 22u)) v00 = *(const ushort8v*)(sw + ry0*2816 + rx0*128);
      else v00 = *(const ushort8v*)(ib + (cy0*128+cx0)*128);
      if (((unsigned)ry0 < 5u) & ((unsigned)rx1 < 22u)) v10 = *(const ushort8v*)(sw + ry0*2816 + rx1*128);
      else v10 = *(const ushort8v*)(ib + (cy0*128+cx1)*128);
      if (((unsigned)ry1 < 5u) & ((unsigned)rx0 < 22u)) v01 = *(const ushort8v*)(sw + ry1*2816 + rx0*128);
      else v01 = *(const ushort8v*)(ib + (cy1*128+cx0)*128);
      if (((unsigned)ry1 < 5u) & ((unsigned)rx1 < 22u)) v11 = *(const ushort8v*)(sw + ry1*2816 + rx1*128);
      else v11 = *(const ushort8v*)(ib + (cy1*128+cx1)*128);
      #pragma unroll
      for (int jj=0;jj<8;jj++){
        float s = wx00*b2f(v00[jj]) + wx10*b2f(v10[jj]) + wx01*b2f(v01[jj]) + wx11*b2f(v11[jj]);
        acc[jj] += s;
      }
    }
    ushort8v outv;
    #pragma unroll
    for (int jj=0;jj<8;jj++) outv[jj] = f2b(acc[jj]);
    *(ushort8v*)(dcnout + (size_t)(pos0+pp)*128 + ch0) = outv;
  }
}

// ---------------- kEFG (r9 champion, verbatim): M=64 weight-amortized fused block ----
__global__ __launch_bounds__(256) void kEFG(const ushort_t* __restrict__ dcnout,
    const ushort_t* __restrict__ pwh, const ushort_t* __restrict__ pwl,
    const float* __restrict__ pb, const float* __restrict__ x,
    const float* __restrict__ n2w, const float* __restrict__ n2b,
    const ushort_t* __restrict__ w1b, const float* __restrict__ b1,
    const ushort_t* __restrict__ w2b, const float* __restrict__ b2,
    float* __restrict__ out){
  __shared__ __align__(16) char dxn[64*256];    // 16 KB: dcnout stage, then xn (in-place)
  __shared__ __align__(16) char hidb[64*256];   // 16 KB: FC1 n-chunk; stats alias early
  float* partS = (float*)hidb;                  // 64*17
  float* partQ = partS + 64*17;
  float* msh   = partQ + 64*17;                 // 64
  float* rsh   = msh + 64;                      // 64   (9216 B < 16384, dead before FC1)

  int t = threadIdx.x;
  int pos0 = blockIdx.x*64;
  int n = pos0>>14, hw0 = pos0&16383;
  int wave = t>>6, lane = t&63;
  int ma = lane&15, quad = lane>>4;

  #pragma unroll
  for (int i=0;i<4;i++){
    int e = i*256 + t;
    int row = e>>4, c16 = e&15;
    ushort8v v = *(const ushort8v*)(dcnout + (size_t)pos0*128 + (size_t)e*8);
    *(ushort8v*)(dxn + XSW(row, c16*16)) = v;
  }
  __syncthreads();

  f32x4 acc[2][4];
  #pragma unroll
  for (int i=0;i<2;i++)
    #pragma unroll
    for (int mt=0; mt<4; mt++) acc[i][mt] = (f32x4){0.f,0.f,0.f,0.f};
  #pragma unroll
  for (int tile=0; tile<2; tile++){
    int c0 = wave*32 + tile*16;
    const ushort_t* bh = pwh + (size_t)(c0 + ma)*128 + quad*8;
    const ushort_t* bl = pwl + (size_t)(c0 + ma)*128 + quad*8;
    short8 bfh[4], bfl[4];
    #pragma unroll
    for (int ks=0; ks<4; ks++){
      bfh[ks] = *(const short8*)(bh + ks*32);
      bfl[ks] = *(const short8*)(bl + ks*32);
    }
    #pragma unroll
    for (int mt=0; mt<4; mt++){
      short8 a[4];
      #pragma unroll
      for (int ks=0; ks<4; ks++)
        a[ks] = *(const short8*)(dxn + XSW(mt*16+ma, ks*64 + quad*16));
      #pragma unroll
      for (int ks=0; ks<4; ks++){
        acc[tile][mt] = __builtin_amdgcn_mfma_f32_16x16x32_bf16(bfh[ks], a[ks], acc[tile][mt], 0,0,0);
        acc[tile][mt] = __builtin_amdgcn_mfma_f32_16x16x32_bf16(bfl[ks], a[ks], acc[tile][mt], 0,0,0);
      }
    }
  }

  ushort4v vbp[2][4];
  float sAcc[4], qAcc[4];
  #pragma unroll
  for (int mt=0; mt<4; mt++){ sAcc[mt]=0.f; qAcc[mt]=0.f; }
  #pragma unroll
  for (int tile=0; tile<2; tile++){
    int c0 = wave*32 + tile*16 + quad*4;
    f32x4 bias4 = *(const f32x4*)(pb + c0);
    #pragma unroll
    for (int mt=0; mt<4; mt++){
      int p = mt*16 + ma;
      ushort4v ov;
      #pragma unroll
      for (int r=0;r<4;r++){
        float res = x[((size_t)(n*128) + c0 + r)*HWsz + hw0 + p];
        float v = acc[tile][mt][r] + bias4[r] + res;
        ushort_t ub = f2b(v);
        ov[r] = ub;
        float vv = b2f(ub);
        sAcc[mt] += vv; qAcc[mt] += vv*vv;
      }
      vbp[tile][mt] = ov;
    }
  }
  #pragma unroll
  for (int mt=0; mt<4; mt++){
    int p = mt*16 + ma;
    partS[p*17 + wave*4 + quad] = sAcc[mt];
    partQ[p*17 + wave*4 + quad] = qAcc[mt];
  }
  __syncthreads();
  {
    int p = t>>2, j = t&3;
    float s = partS[p*17+4*j] + partS[p*17+4*j+1] + partS[p*17+4*j+2] + partS[p*17+4*j+3];
    float q = partQ[p*17+4*j] + partQ[p*17+4*j+1] + partQ[p*17+4*j+2] + partQ[p*17+4*j+3];
    s += __shfl_xor(s, 1);  q += __shfl_xor(q, 1);
    s += __shfl_xor(s, 2);  q += __shfl_xor(q, 2);
    if (j == 0){
      float m = s*(1.0f/128.0f);
      float var = q*(1.0f/128.0f) - m*m;
      msh[p] = m; rsh[p] = rsqrtf(var+1e-6f);
    }
  }
  __syncthreads();

  #pragma unroll
  for (int tile=0; tile<2; tile++){
    int c0 = wave*32 + tile*16 + quad*4;
    f32x4 w4 = *(const f32x4*)(n2w + c0);
    f32x4 b4 = *(const f32x4*)(n2b + c0);
    #pragma unroll
    for (int mt=0; mt<4; mt++){
      int p = mt*16 + ma;
      float m = msh[p], r = rsh[p];
      ushort4v nv;
      #pragma unroll
      for (int rr=0;rr<4;rr++) nv[rr] = f2b((b2f(vbp[tile][mt][rr])-m)*r*w4[rr] + b4[rr]);
      *(ushort4v*)(dxn + XSW(p, c0*2)) = nv;
    }
  }
  __syncthreads();

  f32x4 acc2[2][4];
  #pragma unroll
  for (int i=0;i<2;i++)
    #pragma unroll
    for (int mt=0; mt<4; mt++) acc2[i][mt] = (f32x4){0.f,0.f,0.f,0.f};

  #pragma unroll
  for (int nc=0; nc<4; nc++){
    #pragma unroll
    for (int tt=0; tt<2; tt++){
      int n0g = nc*128 + wave*32 + tt*16;
      const ushort_t* brow = w1b + (size_t)(n0g + ma)*128 + quad*8;
      short8 bf[4];
      #pragma unroll
      for (int ks=0; ks<4; ks++) bf[ks] = *(const short8*)(brow + ks*32);
      int n0 = n0g + quad*4;
      f32x4 bias4 = *(const f32x4*)(b1 + n0);
      int nloc = wave*32 + tt*16 + quad*4;
      #pragma unroll
      for (int mt=0; mt<4; mt++){
        short8 a[4];
        #pragma unroll
        for (int ks=0; ks<4; ks++)
          a[ks] = *(const short8*)(dxn + XSW(mt*16+ma, ks*64 + quad*16));
        f32x4 a0 = (f32x4){0.f,0.f,0.f,0.f};
        #pragma unroll
        for (int ks=0; ks<4; ks++)
          a0 = __builtin_amdgcn_mfma_f32_16x16x32_bf16(bf[ks], a[ks], a0, 0,0,0);
        ushort4v hv;
        #pragma unroll
        for (int r=0;r<4;r++) hv[r] = f2b(gelu_fast(a0[r] + bias4[r]));
        *(ushort4v*)(hidb + XSW(mt*16+ma, nloc*2)) = hv;
      }
    }
    __syncthreads();

    #pragma unroll
    for (int ksl=0; ksl<4; ksl++){
      int kk = nc*128 + ksl*32;
      short8 wc0 = *(const short8*)(w2b + (size_t)(wave*32 + ma)*512 + kk + quad*8);
      short8 wc1 = *(const short8*)(w2b + (size_t)(wave*32 + 16 + ma)*512 + kk + quad*8);
      #pragma unroll
      for (int mt=0; mt<4; mt++){
        short8 hc = *(const short8*)(hidb + XSW(mt*16+ma, ksl*64 + quad*16));
        acc2[0][mt] = __builtin_amdgcn_mfma_f32_16x16x32_bf16(wc0, hc, acc2[0][mt], 0,0,0);
        acc2[1][mt] = __builtin_amdgcn_mfma_f32_16x16x32_bf16(wc1, hc, acc2[1][mt], 0,0,0);
      }
    }
    if (nc < 3) __syncthreads();
  }

  #pragma unroll
  for (int tile=0; tile<2; tile++){
    int c0 = wave*32 + tile*16 + quad*4;
    f32x4 bias4 = *(const f32x4*)(b2 + c0);
    #pragma unroll
    for (int mt=0; mt<4; mt++){
      int p = mt*16 + ma;
      #pragma unroll
      for (int r=0;r<4;r++){
        float v = acc2[tile][mt][r] + bias4[r] + b2f(vbp[tile][mt][r]);
        out[((size_t)(n*128) + c0 + r)*HWsz + hw0 + p] = v;
      }
    }
  }
}

extern "C" void kernel_launch(void* const* d_in, const int* in_sizes, int n_in,
                              void* d_out, int out_size, void* d_ws, size_t ws_size,
                              hipStream_t stream){
  const float* x     = (const float*)d_in[0];
  const float* n1w   = (const float*)d_in[1];
  const float* n1b   = (const float*)d_in[2];
  const float* dww   = (const float*)d_in[3];
  const float* dwb   = (const float*)d_in[4];
  const float* dwlnw = (const float*)d_in[5];
  const float* dwlnb = (const float*)d_in[6];
  const float* offw  = (const float*)d_in[7];
  const float* offb  = (const float*)d_in[8];
  const float* maskw = (const float*)d_in[9];
  const float* maskb = (const float*)d_in[10];
  const float* pw    = (const float*)d_in[11];
  const float* pb    = (const float*)d_in[12];
  const float* n2w   = (const float*)d_in[13];
  const float* n2b   = (const float*)d_in[14];
  const float* w1    = (const float*)d_in[15];
  const float* b1    = (const float*)d_in[16];
  const float* w2    = (const float*)d_in[17];
  const float* b2    = (const float*)d_in[18];

  // ws layout:
  //  R0 = ws[ 0,16MB): xcl (kA->kB) -> dcnout (kCD->kEFG)
  //  R1 = ws[16,32MB): x1  (kB->kCD)
  //  +32MB: w1b(128K) w2b(128K) owmb(32K) pwh(32K) pwl(32K) bf16; dwwT+obm fp32
  char* wsb = (char*)d_ws;
  ushort_t* R0   = (ushort_t*)(wsb);
  ushort_t* R1   = (ushort_t*)(wsb + (16u<<20));
  ushort_t* w1b  = (ushort_t*)(wsb + (32u<<20));
  ushort_t* w2b  = (ushort_t*)(wsb + (32u<<20) + (128u<<10));
  ushort_t* owmb = (ushort_t*)(wsb + (32u<<20) + (256u<<10));
  ushort_t* pwh  = (ushort_t*)(wsb + (32u<<20) + (288u<<10));
  ushort_t* pwl  = (ushort_t*)(wsb + (32u<<20) + (320u<<10));
  float*    dwwT = (float*)(wsb + (32u<<20) + (352u<<10));
  float*    obm  = (float*)(wsb + (32u<<20) + (358u<<10));
  float* out = (float*)d_out;

  hipLaunchKernelGGL(kW_cvt,  dim3(256),   dim3(256), 0, stream, w1, w2, offw, maskw, dww, pw, offb, maskb, w1b, w2b, owmb, dwwT, pwh, pwl, obm);
  hipLaunchKernelGGL(kA_ln1,  dim3(1024),  dim3(256), 0, stream, x, n1w, n1b, R0);
  hipLaunchKernelGGL(kB_dw,   dim3(4096),  dim3(256), 0, stream, R0, dwwT, dwb, dwlnw, dwlnb, R1);
  hipLaunchKernelGGL(kCD_dcn, dim3(4096),  dim3(256), 0, stream, R1, owmb, obm, R0);
  hipLaunchKernelGGL(kEFG,    dim3(1024),  dim3(256), 0, stream, R0, pwh, pwl, pb, x, n2w, n2b, w1b, b1, w2b, b2, out);
}

// Round 13
// 240.195 us; speedup vs baseline: 1.2862x; 1.2862x over previous
//
#include <hip/hip_runtime.h>

typedef unsigned short ushort_t;
typedef short short8 __attribute__((ext_vector_type(8)));
typedef float f32x4 __attribute__((ext_vector_type(4)));
typedef ushort_t ushort8v __attribute__((ext_vector_type(8)));
typedef ushort_t ushort4v __attribute__((ext_vector_type(4)));

#define HWsz 16384
#define NHWsz 65536
// LDS strides (ushorts) for kA/kB/kCD padded tiles
#define YS 136

__device__ __forceinline__ float b2f(ushort_t u){ return __uint_as_float(((unsigned)u)<<16); }
__device__ __forceinline__ ushort_t f2b(float f){
  unsigned x = __float_as_uint(f);
  x += 0x7fffu + ((x>>16)&1u);
  return (ushort_t)(x>>16);
}
// tanh-form GELU: max |err| vs exact ~3e-4, below bf16 ulp at |x|~1+.
__device__ __forceinline__ float gelu_fast(float x){
  float t = x*x;
  float e = __expf(x*(1.5957691216f + 0.0713548163f*t));
  return x - x*__builtin_amdgcn_rcpf(1.0f + e);
}

// XOR-swizzled LDS byte offsets (row-bit into bank bits).
#define XSW(p, b) ((p)*256 + ((b) ^ (((p)&7)<<4)))   // 256B rows

// ---------------- kW: weight preprocessing (once per launch) ----------------
__global__ __launch_bounds__(256) void kW_cvt(const float* __restrict__ w1, const float* __restrict__ w2,
    const float* __restrict__ offw, const float* __restrict__ maskw, const float* __restrict__ dww,
    const float* __restrict__ pw, const float* __restrict__ offb, const float* __restrict__ mb,
    ushort_t* __restrict__ w1b, ushort_t* __restrict__ w2b, ushort_t* __restrict__ owmb,
    float* __restrict__ dwwT, ushort_t* __restrict__ pwh, ushort_t* __restrict__ pwl,
    float* __restrict__ obm){
  int i = blockIdx.x*256 + threadIdx.x;   // 65536
  w1b[i] = f2b(w1[i]);
  w2b[i] = f2b(w2[i]);
  if (i < 16384){
    int row = i >> 7, k = i & 127;
    float v = 0.f;
    if (row < 72) v = offw[row*128 + k];
    else if (row < 108) v = maskw[(row-72)*128 + k];
    owmb[i] = f2b(v);
    float pv = pw[i];
    ushort_t hi = f2b(pv);
    pwh[i] = hi;
    pwl[i] = f2b(pv - b2f(hi));
  }
  if (i < 1152){
    int k = i >> 7, c = i & 127;
    dwwT[i] = dww[c*9 + k];
  }
  if (i < 128){
    obm[i] = (i < 72) ? offb[i] : ((i < 108) ? mb[i-72] : 0.f);
  }
}

// ---------------- kA: LN1, NCHW fp32 -> NHWC bf16 ----------------
__global__ __launch_bounds__(256) void kA_ln1(const float* __restrict__ x,
    const float* __restrict__ w, const float* __restrict__ b,
    ushort_t* __restrict__ xcl){
  __shared__ float tile[128*66];
  __shared__ float psum[256], psq[256];
  __shared__ float ms[64], rs[64];
  int t = threadIdx.x;
  int pos0 = blockIdx.x * 64;
  int n = pos0 >> 14, hw0 = pos0 & 16383;
  const float* xb = x + (size_t)n*128*HWsz + hw0;
  for (int i=0;i<32;i++){
    int e = i*256+t;
    int c = e>>6, p = e&63;
    tile[c*66+p] = xb[(size_t)c*HWsz + p];
  }
  __syncthreads();
  {
    int part = t>>6, p = t&63;
    float s=0.f, q=0.f;
    for (int c=part*32; c<part*32+32; c++){ float v = tile[c*66+p]; s+=v; q+=v*v; }
    psum[part*64+p]=s; psq[part*64+p]=q;
  }
  __syncthreads();
  if (t<64){
    float s=psum[t]+psum[64+t]+psum[128+t]+psum[192+t];
    float q=psq[t]+psq[64+t]+psq[128+t]+psq[192+t];
    float m = s*(1.0f/128.0f);
    float v = q*(1.0f/128.0f)-m*m;
    ms[t]=m; rs[t]=rsqrtf(v+1e-6f);
  }
  __syncthreads();
  for (int i=0;i<32;i++){
    int e = i*256+t;
    int p = e>>7, c = e&127;
    float v = (tile[c*66+p]-ms[p])*rs[p]*w[c]+b[c];
    xcl[(size_t)(pos0+p)*128 + c] = f2b(v);
  }
}

// ---------------- kB: depthwise 3x3 + bias + LN + GELU ----------------
__global__ __launch_bounds__(256) void kB_dw(const ushort_t* __restrict__ xcl,
    const float* __restrict__ dwwT, const float* __restrict__ dwb,
    const float* __restrict__ lnw, const float* __restrict__ lnb,
    ushort_t* __restrict__ x1){
  __shared__ float partS[16*17], partQ[16*17];
  __shared__ float ms[16], rs[16];
  int t = threadIdx.x;
  int pos0 = blockIdx.x*16;
  int n = pos0>>14, hw0 = pos0&16383, h = hw0>>7, w0 = hw0&127;
  int pp = t>>4, l = t&15, ch0 = l*8;
  int w = w0 + pp;
  float acc[8];
  {
    float4 b0 = *(const float4*)(dwb + ch0);
    float4 b1 = *(const float4*)(dwb + ch0 + 4);
    acc[0]=b0.x; acc[1]=b0.y; acc[2]=b0.z; acc[3]=b0.w;
    acc[4]=b1.x; acc[5]=b1.y; acc[6]=b1.z; acc[7]=b1.w;
  }
  #pragma unroll
  for (int kh=0; kh<3; kh++){
    int hy = h + kh - 1;
    if ((unsigned)hy < 128u){
      #pragma unroll
      for (int kw=0; kw<3; kw++){
        int wx = w + kw - 1;
        if ((unsigned)wx < 128u){
          ushort8v xv = *(const ushort8v*)(xcl + ((size_t)(n*16384 + hy*128 + wx))*128 + ch0);
          const float* wr = dwwT + (kh*3+kw)*128 + ch0;
          float4 w0v = *(const float4*)(wr);
          float4 w1v = *(const float4*)(wr+4);
          acc[0] += b2f(xv[0])*w0v.x; acc[1] += b2f(xv[1])*w0v.y;
          acc[2] += b2f(xv[2])*w0v.z; acc[3] += b2f(xv[3])*w0v.w;
          acc[4] += b2f(xv[4])*w1v.x; acc[5] += b2f(xv[5])*w1v.y;
          acc[6] += b2f(xv[6])*w1v.z; acc[7] += b2f(xv[7])*w1v.w;
        }
      }
    }
  }
  {
    float s=0.f, q=0.f;
    #pragma unroll
    for (int j=0;j<8;j++){ s+=acc[j]; q+=acc[j]*acc[j]; }
    partS[pp*17+l]=s; partQ[pp*17+l]=q;
  }
  __syncthreads();
  {
    int p = t>>4, j = t&15;
    float s = partS[p*17+j];
    float q = partQ[p*17+j];
    s += __shfl_xor(s, 1);  q += __shfl_xor(q, 1);
    s += __shfl_xor(s, 2);  q += __shfl_xor(q, 2);
    s += __shfl_xor(s, 4);  q += __shfl_xor(q, 4);
    s += __shfl_xor(s, 8);  q += __shfl_xor(q, 8);
    if (j == 0){
      float m = s*(1.0f/128.0f);
      float var = q*(1.0f/128.0f) - m*m;
      ms[p]=m; rs[p]=rsqrtf(var+1e-6f);
    }
  }
  __syncthreads();
  {
    float m = ms[pp], r = rs[pp];
    float4 lw0 = *(const float4*)(lnw + ch0);
    float4 lw1 = *(const float4*)(lnw + ch0 + 4);
    float4 lb0 = *(const float4*)(lnb + ch0);
    float4 lb1 = *(const float4*)(lnb + ch0 + 4);
    float lw[8] = {lw0.x,lw0.y,lw0.z,lw0.w,lw1.x,lw1.y,lw1.z,lw1.w};
    float lb[8] = {lb0.x,lb0.y,lb0.z,lb0.w,lb1.x,lb1.y,lb1.z,lb1.w};
    ushort8v o;
    #pragma unroll
    for (int j=0;j<8;j++){
      float v = (acc[j]-m)*r*lw[j]+lb[j];
      o[j] = f2b(gelu_fast(v));
    }
    *(ushort8v*)(x1 + (size_t)(pos0+pp)*128 + ch0) = o;
  }
}

// ---------------- kCD v4: 32 positions/block, lean v2 sampling ----------------
// r12 lesson: LDS window regressed (VGPR 136, occupancy 10.8%, VALU-branchy). Revert to
// v2's lean per-thread-descriptor sampling, and apply the 3x-validated weight-traffic
// lever to kCD itself: owmb (32 KB) was re-read per 16 positions (134 MB grid-wide);
// 32 positions/block halves it and halves per-block fixed overhead (stage/MFMA-weights/
// softmax). Gather VMEM per position unchanged. LDS 24.1 KB -> 6 blocks/CU (gather was
// occupancy-insensitive 5..8 per r11).
#define RS 120
__global__ __launch_bounds__(256) void kCD_dcn(const ushort_t* __restrict__ x1,
    const ushort_t* __restrict__ owmb, const float* __restrict__ obm,
    ushort_t* __restrict__ dcnout){
  __shared__ __align__(16) ushort_t xLb[32*YS];
  __shared__ float raw[32*RS];
  int t = threadIdx.x;
  int pos0 = blockIdx.x*32;
  int n = pos0>>14, hw0 = pos0&16383, h = hw0>>7, w0 = hw0&127;
  const size_t imgbase = (size_t)n*16384*128;

  #pragma unroll
  for (int i=0;i<2;i++){
    int e = i*256 + t;
    *(ushort8v*)(xLb + (e>>4)*YS + (e&15)*8) = *(const ushort8v*)(x1 + (size_t)pos0*128 + (size_t)e*8);
  }
  __syncthreads();

  // MFMA linear, operand-swapped: D-row = weight-row, D-col = position.
  // One owmb read per wave-tile serves BOTH position-tiles (the amortization).
  {
    int wave = t>>6, lane = t&63;
    int ma = lane&15, quad = lane>>4;
    f32x4 acc[2][2];   // [wtile][ptile]
    acc[0][0]=(f32x4){0.f,0.f,0.f,0.f}; acc[0][1]=(f32x4){0.f,0.f,0.f,0.f};
    acc[1][0]=(f32x4){0.f,0.f,0.f,0.f}; acc[1][1]=(f32x4){0.f,0.f,0.f,0.f};
    #pragma unroll
    for (int tile=0; tile<2; tile++){
      const ushort_t* brow = owmb + (size_t)(wave*32 + tile*16 + ma)*128 + quad*8;
      short8 bf[4];
      #pragma unroll
      for (int ks=0; ks<4; ks++) bf[ks] = *(const short8*)(brow + ks*32);
      #pragma unroll
      for (int pt=0; pt<2; pt++){
        #pragma unroll
        for (int ks=0; ks<4; ks++){
          short8 af = *(const short8*)(xLb + (pt*16+ma)*YS + ks*32 + quad*8);
          acc[tile][pt] = __builtin_amdgcn_mfma_f32_16x16x32_bf16(bf[ks], af, acc[tile][pt], 0,0,0);
        }
      }
    }
    #pragma unroll
    for (int tile=0; tile<2; tile++){
      int row0 = wave*32 + tile*16 + quad*4;
      if (row0 < 112){
        f32x4 bias4 = *(const f32x4*)(obm + row0);
        #pragma unroll
        for (int pt=0; pt<2; pt++){
          f32x4 o;
          #pragma unroll
          for (int r=0;r<4;r++) o[r] = acc[tile][pt][r] + bias4[r];
          *(f32x4*)(raw + (pt*16+ma)*RS + row0) = o;
        }
      }
    }
  }
  __syncthreads();

  if (t < 128){
    int p = t>>2, g = t&3;
    float* mr = raw + p*RS + 72 + g*9;
    float mx = -1e30f;
    for (int q=0;q<9;q++) mx = fmaxf(mx, mr[q]);
    float e[9]; float ssum=0.f;
    for (int q=0;q<9;q++){ e[q]=expf(mr[q]-mx); ssum+=e[q]; }
    float inv = 1.0f/ssum;
    for (int q=0;q<9;q++) mr[q] = e[q]*inv;
  }
  __syncthreads();

  // sampling: 2 passes of 16 positions; per-thread descriptors (lean v2 form)
  for (int sp=0; sp<2; sp++){
    int pp = sp*16 + (t>>4), l = t&15;
    int ch0 = l*8, g = l>>2;
    const ushort_t* ib = x1 + imgbase + ch0;
    const float* rbase = raw + pp*RS;
    float acc[8];
    #pragma unroll
    for (int j=0;j<8;j++) acc[j]=0.f;
    float bx = (float)(w0 + pp - 1);
    float by = (float)(h - 1);
    #pragma unroll
    for (int p=0;p<9;p++){
      const int i = p/3, j = p - i*3;
      float ox = rbase[2*(g*9+p)];
      float oy = rbase[2*(g*9+p)+1];
      float mval = rbase[72 + g*9 + p];
      float px = bx + (float)i + ox;
      float py = by + (float)j + oy;
      float fx0 = floorf(px), fy0 = floorf(py);
      int ix0 = (int)fx0, iy0 = (int)fy0;
      float fx = px - fx0, fy = py - fy0;
      float vx0 = ((unsigned)ix0     < 128u) ? 1.f : 0.f;
      float vx1 = ((unsigned)(ix0+1) < 128u) ? 1.f : 0.f;
      float vy0 = ((unsigned)iy0     < 128u) ? 1.f : 0.f;
      float vy1 = ((unsigned)(iy0+1) < 128u) ? 1.f : 0.f;
      int cx0 = min(max(ix0,0),127), cx1 = min(max(ix0+1,0),127);
      int cy0 = min(max(iy0,0),127), cy1 = min(max(iy0+1,0),127);
      float wx00 = (1.f-fx)*(1.f-fy)*mval*vx0*vy0;
      float wx10 = fx*(1.f-fy)*mval*vx1*vy0;
      float wx01 = (1.f-fx)*fy*mval*vx0*vy1;
      float wx11 = fx*fy*mval*vx1*vy1;
      ushort8v v00 = *(const ushort8v*)(ib + (cy0*128+cx0)*128);
      ushort8v v10 = *(const ushort8v*)(ib + (cy0*128+cx1)*128);
      ushort8v v01 = *(const ushort8v*)(ib + (cy1*128+cx0)*128);
      ushort8v v11 = *(const ushort8v*)(ib + (cy1*128+cx1)*128);
      #pragma unroll
      for (int jj=0;jj<8;jj++){
        float s = wx00*b2f(v00[jj]) + wx10*b2f(v10[jj]) + wx01*b2f(v01[jj]) + wx11*b2f(v11[jj]);
        acc[jj] += s;
      }
    }
    ushort8v outv;
    #pragma unroll
    for (int jj=0;jj<8;jj++) outv[jj] = f2b(acc[jj]);
    *(ushort8v*)(dcnout + (size_t)(pos0+pp)*128 + ch0) = outv;
  }
}

// ---------------- kEFG (r9 champion, verbatim): M=64 weight-amortized fused block ----
__global__ __launch_bounds__(256) void kEFG(const ushort_t* __restrict__ dcnout,
    const ushort_t* __restrict__ pwh, const ushort_t* __restrict__ pwl,
    const float* __restrict__ pb, const float* __restrict__ x,
    const float* __restrict__ n2w, const float* __restrict__ n2b,
    const ushort_t* __restrict__ w1b, const float* __restrict__ b1,
    const ushort_t* __restrict__ w2b, const float* __restrict__ b2,
    float* __restrict__ out){
  __shared__ __align__(16) char dxn[64*256];    // 16 KB: dcnout stage, then xn (in-place)
  __shared__ __align__(16) char hidb[64*256];   // 16 KB: FC1 n-chunk; stats alias early
  float* partS = (float*)hidb;                  // 64*17
  float* partQ = partS + 64*17;
  float* msh   = partQ + 64*17;                 // 64
  float* rsh   = msh + 64;                      // 64   (9216 B < 16384, dead before FC1)

  int t = threadIdx.x;
  int pos0 = blockIdx.x*64;
  int n = pos0>>14, hw0 = pos0&16383;
  int wave = t>>6, lane = t&63;
  int ma = lane&15, quad = lane>>4;

  #pragma unroll
  for (int i=0;i<4;i++){
    int e = i*256 + t;
    int row = e>>4, c16 = e&15;
    ushort8v v = *(const ushort8v*)(dcnout + (size_t)pos0*128 + (size_t)e*8);
    *(ushort8v*)(dxn + XSW(row, c16*16)) = v;
  }
  __syncthreads();

  f32x4 acc[2][4];
  #pragma unroll
  for (int i=0;i<2;i++)
    #pragma unroll
    for (int mt=0; mt<4; mt++) acc[i][mt] = (f32x4){0.f,0.f,0.f,0.f};
  #pragma unroll
  for (int tile=0; tile<2; tile++){
    int c0 = wave*32 + tile*16;
    const ushort_t* bh = pwh + (size_t)(c0 + ma)*128 + quad*8;
    const ushort_t* bl = pwl + (size_t)(c0 + ma)*128 + quad*8;
    short8 bfh[4], bfl[4];
    #pragma unroll
    for (int ks=0; ks<4; ks++){
      bfh[ks] = *(const short8*)(bh + ks*32);
      bfl[ks] = *(const short8*)(bl + ks*32);
    }
    #pragma unroll
    for (int mt=0; mt<4; mt++){
      short8 a[4];
      #pragma unroll
      for (int ks=0; ks<4; ks++)
        a[ks] = *(const short8*)(dxn + XSW(mt*16+ma, ks*64 + quad*16));
      #pragma unroll
      for (int ks=0; ks<4; ks++){
        acc[tile][mt] = __builtin_amdgcn_mfma_f32_16x16x32_bf16(bfh[ks], a[ks], acc[tile][mt], 0,0,0);
        acc[tile][mt] = __builtin_amdgcn_mfma_f32_16x16x32_bf16(bfl[ks], a[ks], acc[tile][mt], 0,0,0);
      }
    }
  }

  ushort4v vbp[2][4];
  float sAcc[4], qAcc[4];
  #pragma unroll
  for (int mt=0; mt<4; mt++){ sAcc[mt]=0.f; qAcc[mt]=0.f; }
  #pragma unroll
  for (int tile=0; tile<2; tile++){
    int c0 = wave*32 + tile*16 + quad*4;
    f32x4 bias4 = *(const f32x4*)(pb + c0);
    #pragma unroll
    for (int mt=0; mt<4; mt++){
      int p = mt*16 + ma;
      ushort4v ov;
      #pragma unroll
      for (int r=0;r<4;r++){
        float res = x[((size_t)(n*128) + c0 + r)*HWsz + hw0 + p];
        float v = acc[tile][mt][r] + bias4[r] + res;
        ushort_t ub = f2b(v);
        ov[r] = ub;
        float vv = b2f(ub);
        sAcc[mt] += vv; qAcc[mt] += vv*vv;
      }
      vbp[tile][mt] = ov;
    }
  }
  #pragma unroll
  for (int mt=0; mt<4; mt++){
    int p = mt*16 + ma;
    partS[p*17 + wave*4 + quad] = sAcc[mt];
    partQ[p*17 + wave*4 + quad] = qAcc[mt];
  }
  __syncthreads();
  {
    int p = t>>2, j = t&3;
    float s = partS[p*17+4*j] + partS[p*17+4*j+1] + partS[p*17+4*j+2] + partS[p*17+4*j+3];
    float q = partQ[p*17+4*j] + partQ[p*17+4*j+1] + partQ[p*17+4*j+2] + partQ[p*17+4*j+3];
    s += __shfl_xor(s, 1);  q += __shfl_xor(q, 1);
    s += __shfl_xor(s, 2);  q += __shfl_xor(q, 2);
    if (j == 0){
      float m = s*(1.0f/128.0f);
      float var = q*(1.0f/128.0f) - m*m;
      msh[p] = m; rsh[p] = rsqrtf(var+1e-6f);
    }
  }
  __syncthreads();

  #pragma unroll
  for (int tile=0; tile<2; tile++){
    int c0 = wave*32 + tile*16 + quad*4;
    f32x4 w4 = *(const f32x4*)(n2w + c0);
    f32x4 b4 = *(const f32x4*)(n2b + c0);
    #pragma unroll
    for (int mt=0; mt<4; mt++){
      int p = mt*16 + ma;
      float m = msh[p], r = rsh[p];
      ushort4v nv;
      #pragma unroll
      for (int rr=0;rr<4;rr++) nv[rr] = f2b((b2f(vbp[tile][mt][rr])-m)*r*w4[rr] + b4[rr]);
      *(ushort4v*)(dxn + XSW(p, c0*2)) = nv;
    }
  }
  __syncthreads();

  f32x4 acc2[2][4];
  #pragma unroll
  for (int i=0;i<2;i++)
    #pragma unroll
    for (int mt=0; mt<4; mt++) acc2[i][mt] = (f32x4){0.f,0.f,0.f,0.f};

  #pragma unroll
  for (int nc=0; nc<4; nc++){
    #pragma unroll
    for (int tt=0; tt<2; tt++){
      int n0g = nc*128 + wave*32 + tt*16;
      const ushort_t* brow = w1b + (size_t)(n0g + ma)*128 + quad*8;
      short8 bf[4];
      #pragma unroll
      for (int ks=0; ks<4; ks++) bf[ks] = *(const short8*)(brow + ks*32);
      int n0 = n0g + quad*4;
      f32x4 bias4 = *(const f32x4*)(b1 + n0);
      int nloc = wave*32 + tt*16 + quad*4;
      #pragma unroll
      for (int mt=0; mt<4; mt++){
        short8 a[4];
        #pragma unroll
        for (int ks=0; ks<4; ks++)
          a[ks] = *(const short8*)(dxn + XSW(mt*16+ma, ks*64 + quad*16));
        f32x4 a0 = (f32x4){0.f,0.f,0.f,0.f};
        #pragma unroll
        for (int ks=0; ks<4; ks++)
          a0 = __builtin_amdgcn_mfma_f32_16x16x32_bf16(bf[ks], a[ks], a0, 0,0,0);
        ushort4v hv;
        #pragma unroll
        for (int r=0;r<4;r++) hv[r] = f2b(gelu_fast(a0[r] + bias4[r]));
        *(ushort4v*)(hidb + XSW(mt*16+ma, nloc*2)) = hv;
      }
    }
    __syncthreads();

    #pragma unroll
    for (int ksl=0; ksl<4; ksl++){
      int kk = nc*128 + ksl*32;
      short8 wc0 = *(const short8*)(w2b + (size_t)(wave*32 + ma)*512 + kk + quad*8);
      short8 wc1 = *(const short8*)(w2b + (size_t)(wave*32 + 16 + ma)*512 + kk + quad*8);
      #pragma unroll
      for (int mt=0; mt<4; mt++){
        short8 hc = *(const short8*)(hidb + XSW(mt*16+ma, ksl*64 + quad*16));
        acc2[0][mt] = __builtin_amdgcn_mfma_f32_16x16x32_bf16(wc0, hc, acc2[0][mt], 0,0,0);
        acc2[1][mt] = __builtin_amdgcn_mfma_f32_16x16x32_bf16(wc1, hc, acc2[1][mt], 0,0,0);
      }
    }
    if (nc < 3) __syncthreads();
  }

  #pragma unroll
  for (int tile=0; tile<2; tile++){
    int c0 = wave*32 + tile*16 + quad*4;
    f32x4 bias4 = *(const f32x4*)(b2 + c0);
    #pragma unroll
    for (int mt=0; mt<4; mt++){
      int p = mt*16 + ma;
      #pragma unroll
      for (int r=0;r<4;r++){
        float v = acc2[tile][mt][r] + bias4[r] + b2f(vbp[tile][mt][r]);
        out[((size_t)(n*128) + c0 + r)*HWsz + hw0 + p] = v;
      }
    }
  }
}

extern "C" void kernel_launch(void* const* d_in, const int* in_sizes, int n_in,
                              void* d_out, int out_size, void* d_ws, size_t ws_size,
                              hipStream_t stream){
  const float* x     = (const float*)d_in[0];
  const float* n1w   = (const float*)d_in[1];
  const float* n1b   = (const float*)d_in[2];
  const float* dww   = (const float*)d_in[3];
  const float* dwb   = (const float*)d_in[4];
  const float* dwlnw = (const float*)d_in[5];
  const float* dwlnb = (const float*)d_in[6];
  const float* offw  = (const float*)d_in[7];
  const float* offb  = (const float*)d_in[8];
  const float* maskw = (const float*)d_in[9];
  const float* maskb = (const float*)d_in[10];
  const float* pw    = (const float*)d_in[11];
  const float* pb    = (const float*)d_in[12];
  const float* n2w   = (const float*)d_in[13];
  const float* n2b   = (const float*)d_in[14];
  const float* w1    = (const float*)d_in[15];
  const float* b1    = (const float*)d_in[16];
  const float* w2    = (const float*)d_in[17];
  const float* b2    = (const float*)d_in[18];

  // ws layout:
  //  R0 = ws[ 0,16MB): xcl (kA->kB) -> dcnout (kCD->kEFG)
  //  R1 = ws[16,32MB): x1  (kB->kCD)
  //  +32MB: w1b(128K) w2b(128K) owmb(32K) pwh(32K) pwl(32K) bf16; dwwT+obm fp32
  char* wsb = (char*)d_ws;
  ushort_t* R0   = (ushort_t*)(wsb);
  ushort_t* R1   = (ushort_t*)(wsb + (16u<<20));
  ushort_t* w1b  = (ushort_t*)(wsb + (32u<<20));
  ushort_t* w2b  = (ushort_t*)(wsb + (32u<<20) + (128u<<10));
  ushort_t* owmb = (ushort_t*)(wsb + (32u<<20) + (256u<<10));
  ushort_t* pwh  = (ushort_t*)(wsb + (32u<<20) + (288u<<10));
  ushort_t* pwl  = (ushort_t*)(wsb + (32u<<20) + (320u<<10));
  float*    dwwT = (float*)(wsb + (32u<<20) + (352u<<10));
  float*    obm  = (float*)(wsb + (32u<<20) + (358u<<10));
  float* out = (float*)d_out;

  hipLaunchKernelGGL(kW_cvt,  dim3(256),   dim3(256), 0, stream, w1, w2, offw, maskw, dww, pw, offb, maskb, w1b, w2b, owmb, dwwT, pwh, pwl, obm);
  hipLaunchKernelGGL(kA_ln1,  dim3(1024),  dim3(256), 0, stream, x, n1w, n1b, R0);
  hipLaunchKernelGGL(kB_dw,   dim3(4096),  dim3(256), 0, stream, R0, dwwT, dwb, dwlnw, dwlnb, R1);
  hipLaunchKernelGGL(kCD_dcn, dim3(2048),  dim3(256), 0, stream, R1, owmb, obm, R0);
  hipLaunchKernelGGL(kEFG,    dim3(1024),  dim3(256), 0, stream, R0, pwh, pwl, pb, x, n2w, n2b, w1b, b1, w2b, b2, out);
}